// Round 1
// 206.518 us; speedup vs baseline: 1.0186x; 1.0186x over previous
//
#include <hip/hip_runtime.h>
#include <hip/hip_bf16.h>

// OneStep: out = W - c * K^T (K W - V),  c = 0.2/(CTX*D) = 9.5367431640625e-8
// W:(4096,4096) K:(512,4096) V:(512,4096) fp32 -> out (4096,4096) fp32.
// bf16 MFMA w/ fp32 acc => absmax 2.441e-4 = 1 bf16 ulp (threshold 1.69e-3).
//
// R6 post-mortem: k2 at 53 us with MfmaUtil 11.8%, HBM 28%, Occ 17% --
// latency-bound: each K-step drains vmcnt(0) via __syncthreads right after
// issuing its staging loads (16 exposed round-trips/block). k1 has the same
// issue-then-wait shape (no tile in flight ahead).
// R7: software-pipeline one K-tile ahead (guide T3-min/T4):
//   k2: double-buffered LDS (32 KB), ONE barrier per K-step, stage(t+1)
//       issued before compute(t); epilogue ep[32][132] still aliases buf0.
//   k1: per-wave double-buffer (64 KB total = 2 blocks/CU, matches grid),
//       counted vmcnt(12)/vmcnt(8) steady-state -- never drain to 0 in-loop.

typedef __bf16 bf16_t;
typedef __bf16 bf16x8 __attribute__((ext_vector_type(8)));
typedef float f32x4 __attribute__((ext_vector_type(4)));

#define D_DIM 4096
#define CTX_N 512
#define UPD_SCALE 9.5367431640625e-8f

__device__ __forceinline__ void gld16(const bf16_t* g, bf16_t* l) {
    __builtin_amdgcn_global_load_lds(
        (const __attribute__((address_space(1))) void*)g,
        (__attribute__((address_space(3))) void*)l, 16, 0, 0);
}

// ---- transpose+convert: src (M x N) fp32 tile -> dstT (N x M) bf16
//      [+ dstN (M x N) bf16].  64x64 tile at (bx,by); pad-65 (2-way = free).
__device__ __forceinline__ void t_body2(
    float* tile, const float* __restrict__ src, bf16_t* __restrict__ dstT,
    bf16_t* __restrict__ dstN, int M, int N, int bx, int by)
{
    const int tid = threadIdx.x;
    const int C0 = bx * 64, R0 = by * 64;
    const int r  = tid >> 2, cs = (tid & 3) * 16;

    const float* s = src + (size_t)(R0 + r) * N + C0 + cs;
    float f[16];
#pragma unroll
    for (int u = 0; u < 4; ++u) {
        const float4 v = ((const float4*)s)[u];
        f[4 * u + 0] = v.x; f[4 * u + 1] = v.y; f[4 * u + 2] = v.z; f[4 * u + 3] = v.w;
    }
#pragma unroll
    for (int u = 0; u < 16; ++u) tile[r * 65 + cs + u] = f[u];

    if (dstN) {
        bf16x8 v0, v1;
#pragma unroll
        for (int u = 0; u < 8; ++u) { v0[u] = (bf16_t)f[u]; v1[u] = (bf16_t)f[8 + u]; }
        bf16_t* d = dstN + (size_t)(R0 + r) * N + C0 + cs;
        *(bf16x8*)d = v0; *(bf16x8*)(d + 8) = v1;
    }
    __syncthreads();

    bf16x8 o0, o1;
#pragma unroll
    for (int u = 0; u < 8; ++u) {
        o0[u] = (bf16_t)tile[(cs + u) * 65 + r];
        o1[u] = (bf16_t)tile[(cs + 8 + u) * 65 + r];
    }
    bf16_t* d = dstT + (size_t)(C0 + r) * M + R0 + cs;
    *(bf16x8*)d = o0; *(bf16x8*)(d + 8) = o1;
}

// One launch for all three transposes: y<64 -> W, 64..71 -> K(+Kb), 72..79 -> V
__global__ __launch_bounds__(256) void t_all(
    const float* __restrict__ W, const float* __restrict__ K,
    const float* __restrict__ V, bf16_t* __restrict__ Wt,
    bf16_t* __restrict__ Kt, bf16_t* __restrict__ Kb, bf16_t* __restrict__ Vt)
{
    __shared__ float tile[64 * 65];
    const int y = blockIdx.y;
    if (y < 64)      t_body2(tile, W, Wt, nullptr, D_DIM, D_DIM, blockIdx.x, y);
    else if (y < 72) t_body2(tile, K, Kt, Kb,      CTX_N, D_DIM, blockIdx.x, y - 64);
    else             t_body2(tile, V, Vt, nullptr, CTX_N, D_DIM, blockIdx.x, y - 72);
}

// MFMA 16x16x32 bf16 (m89/m91): A/B frag: row=lane&15, k=quad*8+j (8 bf16);
// C/D: col=lane&15, row=quad*4+reg.  D[m][n] = sum_k A(m,k)*B(n,k).

// ---- K1: Rt[j][c] = sum_k Wt[j][k]*Kb[c][k] - Vt[j][c]  (4096 x 512) ----
// Barrier-free K-split: wave w owns k in [w*1024, w*1024+1024), 64x64 tile,
// per-wave DOUBLE-BUFFERED private staging (A0 B0 A1 B1, 4 KB each).
// Counted vmcnt: steady state waits vmcnt(12) (A of current tile) then
// vmcnt(8) (B of current tile) while the next tile's 8 loads stay in flight.
// grid (64 j, 8 c): id%8 = j%8 pins the 8 c-sharers of a Wt slice to one XCD.

#define K1_COMPUTE(BSEL, WA, WB)                                             \
    {                                                                        \
        const bf16_t* As = (const bf16_t*)(reg + (BSEL) * 8192);             \
        const bf16_t* Bs = (const bf16_t*)(reg + 4096 + (BSEL) * 8192);      \
        __builtin_amdgcn_s_waitcnt(WA);                                      \
        bf16x8 af[4];                                                        \
        _Pragma("unroll")                                                    \
        for (int mi = 0; mi < 4; ++mi)                                       \
            af[mi] = *(const bf16x8*)(As + (mi * 16 + l15) * 32 + quad * 8); \
        __builtin_amdgcn_s_waitcnt(WB);                                      \
        bf16x8 bq[4];                                                        \
        _Pragma("unroll")                                                    \
        for (int ni = 0; ni < 4; ++ni)                                       \
            bq[ni] = *(const bf16x8*)(Bs + (ni * 16 + l15) * 32 + quad * 8); \
        _Pragma("unroll")                                                    \
        for (int mi = 0; mi < 4; ++mi)                                       \
            _Pragma("unroll")                                                \
            for (int ni = 0; ni < 4; ++ni)                                   \
                acc[mi][ni] = __builtin_amdgcn_mfma_f32_16x16x32_bf16(       \
                    af[mi], bq[ni], acc[mi][ni], 0, 0, 0);                   \
    }

__global__ __launch_bounds__(256) void k1_residual(
    const bf16_t* __restrict__ Wt, const bf16_t* __restrict__ Kb,
    const bf16_t* __restrict__ Vt, bf16_t* __restrict__ Rt)
{
    __shared__ __align__(16) char smem[65536];  // 4 waves x (A0 B0 A1 B1)

    const int tid = threadIdx.x, wave = tid >> 6, lane = tid & 63;
    const int j0 = blockIdx.x * 64, c0 = blockIdx.y * 64;
    const int l15 = lane & 15, quad = lane >> 4;
    const int kw = wave * 1024;

    char* reg = smem + wave * 16384;  // private per-wave staging region

    f32x4 acc[4][4] = {};

    const int srow = lane >> 2, sseg = (lane & 3) * 8;   // 16 rows / gld16 call
    const bf16_t* ga = Wt + (size_t)(j0 + srow) * D_DIM + kw + sseg;
    const bf16_t* gb = Kb + (size_t)(c0 + srow) * D_DIM + kw + sseg;

    auto stageA = [&](int bsel, int ko) {
        bf16_t* la = (bf16_t*)(reg + bsel * 8192) + lane * 8;
#pragma unroll
        for (int c = 0; c < 4; ++c)
            gld16(ga + ko + (size_t)(c * 16) * D_DIM, la + c * 512);
    };
    auto stageB = [&](int bsel, int ko) {
        bf16_t* lb = (bf16_t*)(reg + 4096 + bsel * 8192) + lane * 8;
#pragma unroll
        for (int c = 0; c < 4; ++c)
            gld16(gb + ko + (size_t)(c * 16) * D_DIM, lb + c * 512);
    };

    // 32 K-tiles of 32. Prologue: tile 0 -> buf0 (8 loads outstanding).
    stageA(0, 0); stageB(0, 0);
#pragma unroll 1
    for (int t = 1; t <= 29; t += 2) {
        stageA(1, t * 32); stageB(1, t * 32);
        __builtin_amdgcn_sched_barrier(0);
        K1_COMPUTE(0, 0x0f7c, 0x0f78);            // tile t-1: vmcnt(12)/(8)
        stageA(0, (t + 1) * 32); stageB(0, (t + 1) * 32);
        __builtin_amdgcn_sched_barrier(0);
        K1_COMPUTE(1, 0x0f7c, 0x0f78);            // tile t
    }
    stageA(1, 31 * 32); stageB(1, 31 * 32);
    __builtin_amdgcn_sched_barrier(0);
    K1_COMPUTE(0, 0x0f7c, 0x0f78);                // tile 30
    K1_COMPUTE(1, 0x0f74, 0x0f70);                // tile 31: vmcnt(4)/(0)

    // Cross-wave reduction: ep[64][68] f32 (17.4 KB) aliases dead staging.
    float* ep = (float*)smem;
    __syncthreads();
#pragma unroll
    for (int w = 0; w < 4; ++w) {
        if (wave == w) {
#pragma unroll
            for (int mi = 0; mi < 4; ++mi)
#pragma unroll
                for (int ni = 0; ni < 4; ++ni)
#pragma unroll
                    for (int r = 0; r < 4; ++r) {
                        const int row = mi * 16 + quad * 4 + r;
                        const int col = ni * 16 + l15;
                        if (w == 0) ep[row * 68 + col]  = acc[mi][ni][r];
                        else        ep[row * 68 + col] += acc[mi][ni][r];
                    }
        }
        __syncthreads();
    }

    // Epilogue: Rt = ep - Vt, vectorized.
    {
        const int row = tid >> 2, cs = (tid & 3) * 16;
        const size_t rbase = (size_t)(j0 + row) * CTX_N + c0 + cs;
        float e[16];
#pragma unroll
        for (int u = 0; u < 4; ++u) {
            const float4 v = ((const float4*)(ep + row * 68 + cs))[u];
            e[4 * u + 0] = v.x; e[4 * u + 1] = v.y;
            e[4 * u + 2] = v.z; e[4 * u + 3] = v.w;
        }
        const bf16x8 v0 = *(const bf16x8*)(Vt + rbase);
        const bf16x8 v1 = *(const bf16x8*)(Vt + rbase + 8);
        bf16x8 o0, o1;
#pragma unroll
        for (int u = 0; u < 8; ++u) {
            o0[u] = (bf16_t)(e[u]     - (float)v0[u]);
            o1[u] = (bf16_t)(e[8 + u] - (float)v1[u]);
        }
        *(bf16x8*)(Rt + rbase)     = o0;
        *(bf16x8*)(Rt + rbase + 8) = o1;
    }
}

// ---- K2: out[i][j] = W[i][j] - c * sum_c Kt[i][c]*Rt[j][c]  (4096x4096) ----
// 128x128 tile, BK=32, 4 waves of 64x64. DOUBLE-BUFFERED staging (2x16 KB):
// stage(t+1) issued before compute(t); ONE __syncthreads per K-step (its
// vmcnt(0) drain lands after ~300cyc of ds_read+MFMA cover). Epilogue
// transpose buffer ep[32][132] aliases buf0, 4 passes of 32 rows with
// per-pass W float4 prefetch.

#define K2_COMPUTE(BSEL)                                                     \
    {                                                                        \
        const bf16_t* As = (const bf16_t*)(smem + (BSEL) * 16384);           \
        const bf16_t* Bs = (const bf16_t*)(smem + (BSEL) * 16384 + 8192);    \
        bf16x8 af[4], bq[4];                                                 \
        _Pragma("unroll")                                                    \
        for (int mi = 0; mi < 4; ++mi)                                       \
            af[mi] = *(const bf16x8*)(As + (wi + mi * 16 + l15) * 32 + quad * 8); \
        _Pragma("unroll")                                                    \
        for (int ni = 0; ni < 4; ++ni)                                       \
            bq[ni] = *(const bf16x8*)(Bs + (wj + ni * 16 + l15) * 32 + quad * 8); \
        _Pragma("unroll")                                                    \
        for (int mi = 0; mi < 4; ++mi)                                       \
            _Pragma("unroll")                                                \
            for (int ni = 0; ni < 4; ++ni)                                   \
                acc[mi][ni] = __builtin_amdgcn_mfma_f32_16x16x32_bf16(       \
                    af[mi], bq[ni], acc[mi][ni], 0, 0, 0);                   \
    }

__global__ __launch_bounds__(256) void k2_update(
    const bf16_t* __restrict__ Kt, const bf16_t* __restrict__ Rt,
    const float* __restrict__ W, float* __restrict__ out)
{
    __shared__ __align__(16) char smem[32768];  // buf0 16KB | buf1 16KB

    const int tid = threadIdx.x;
    const int j0 = blockIdx.x * 128, i0 = blockIdx.y * 128;
    const int lane = tid & 63, wave = tid >> 6;
    const int wi = (wave >> 1) * 64, wj = (wave & 1) * 64;
    const int l15 = lane & 15, quad = lane >> 4;

    f32x4 acc[4][4] = {};

    const bf16_t* ga = Kt + (size_t)(i0 + (tid >> 2)) * CTX_N + (tid & 3) * 8;
    const bf16_t* gb = Rt + (size_t)(j0 + (tid >> 2)) * CTX_N + (tid & 3) * 8;

    auto stage = [&](int bsel, int cc) {
        bf16_t* la = (bf16_t*)(smem + bsel * 16384) + tid * 8;
        bf16_t* lb = (bf16_t*)(smem + bsel * 16384 + 8192) + tid * 8;
        gld16(ga + cc, la);
        gld16(ga + cc + (size_t)64 * CTX_N, la + 64 * 32);
        gld16(gb + cc, lb);
        gld16(gb + cc + (size_t)64 * CTX_N, lb + 64 * 32);
    };

    // 16 K-tiles of 32. Prologue: tile 0 -> buf0.
    stage(0, 0);
    __syncthreads();
#pragma unroll 1
    for (int t = 1; t <= 13; t += 2) {
        stage(1, t * 32);
        __builtin_amdgcn_sched_barrier(0);
        K2_COMPUTE(0);                  // tile t-1
        __syncthreads();
        stage(0, (t + 1) * 32);
        __builtin_amdgcn_sched_barrier(0);
        K2_COMPUTE(1);                  // tile t
        __syncthreads();
    }
    stage(1, 15 * 32);
    __builtin_amdgcn_sched_barrier(0);
    K2_COMPUTE(0);                      // tile 14
    __syncthreads();
    K2_COMPUTE(1);                      // tile 15
    __syncthreads();

    // Epilogue: 4 passes x 32 rows through ep[32][132] (aliases buf0).
    float* ep = (float*)smem;
    const int row = tid >> 3;          // 0..31
    const int cb  = (tid & 7) * 16;    // 0,16,...,112
#pragma unroll
    for (int p = 0; p < 4; ++p) {
        // Prefetch W for this pass (drains during the LDS transpose+barrier).
        const float* wrow = W + (size_t)(i0 + p * 32 + row) * D_DIM + j0 + cb;
        float4 wv[4];
#pragma unroll
        for (int u = 0; u < 4; ++u) wv[u] = ((const float4*)wrow)[u];

        if ((wave >> 1) == (p >> 1)) {
#pragma unroll
            for (int mh = 0; mh < 2; ++mh) {
                const int mi = (p & 1) * 2 + mh;
#pragma unroll
                for (int ni = 0; ni < 4; ++ni)
#pragma unroll
                    for (int r = 0; r < 4; ++r)
                        ep[(mh * 16 + quad * 4 + r) * 132 + wj + ni * 16 + l15] =
                            acc[mi][ni][r];
            }
        }
        __syncthreads();
        {
            float* orow = out + (size_t)(i0 + p * 32 + row) * D_DIM + j0 + cb;
            const float* erow = ep + row * 132 + cb;
#pragma unroll
            for (int u = 0; u < 4; ++u) {
                const float4 ev = ((const float4*)erow)[u];
                float4 ov;
                ov.x = wv[u].x - UPD_SCALE * ev.x;
                ov.y = wv[u].y - UPD_SCALE * ev.y;
                ov.z = wv[u].z - UPD_SCALE * ev.z;
                ov.w = wv[u].w - UPD_SCALE * ev.w;
                ((float4*)orow)[u] = ov;
            }
        }
        __syncthreads();
    }
}

extern "C" void kernel_launch(void* const* d_in, const int* in_sizes, int n_in,
                              void* d_out, int out_size, void* d_ws, size_t ws_size,
                              hipStream_t stream) {
    const float* W = (const float*)d_in[0];   // (4096, 4096)
    const float* K = (const float*)d_in[1];   // (512, 4096)
    const float* V = (const float*)d_in[2];   // (512, 4096)
    float* out = (float*)d_out;

    char* ws = (char*)d_ws;                    // 48 MB used
    bf16_t* Wt = (bf16_t*)(ws);                            // (4096,4096) W^T
    bf16_t* Kt = (bf16_t*)(ws + (size_t)32 * 1024 * 1024); // (4096,512) K^T
    bf16_t* Kb = (bf16_t*)(ws + (size_t)36 * 1024 * 1024); // (512,4096) K
    bf16_t* Vt = (bf16_t*)(ws + (size_t)40 * 1024 * 1024); // (4096,512) V^T
    bf16_t* Rt = (bf16_t*)(ws + (size_t)44 * 1024 * 1024); // (4096,512) R^T

    t_all      <<<dim3(64, 80), 256, 0, stream>>>(W, K, V, Wt, Kt, Kb, Vt);
    k1_residual<<<dim3(64, 8),  256, 0, stream>>>(Wt, Kb, Vt, Rt);
    k2_update  <<<dim3(32, 32), 256, 0, stream>>>(Kt, Rt, W, out);
}

// Round 2
// 199.680 us; speedup vs baseline: 1.0535x; 1.0342x over previous
//
#include <hip/hip_runtime.h>
#include <hip/hip_bf16.h>

// OneStep: out = W - c * K^T (K W - V),  c = 0.2/(CTX*D) = 9.5367431640625e-8
// W:(4096,4096) K:(512,4096) V:(512,4096) fp32 -> out (4096,4096) fp32.
// bf16 MFMA w/ fp32 acc => absmax 2.441e-4 = 1 bf16 ulp (threshold 1.69e-3).
//
// R7 post-mortem: k2 53->45 us (db pipeline worked) but still 2x above its
// ~21 us BW floor. 118/122 MB of k2's HBM traffic is the EPILOGUE, which was
// 4 passes x 2 barriers of block-wide LDS transpose -- memory pipe drains at
// every barrier, 4 blocks/CU can't cover.
// R8: barrier-free direct epilogue -- per-fragment W load (prefetched one
// mi-block ahead), FMA, dword store. 16-lane 64B segments; adjacent ni
// segments complete each 256B row chunk -> L2 merges. Plus bijective XCD
// swizzle so the 32 blocks sharing a Kt i-slice share one XCD L2.

typedef __bf16 bf16_t;
typedef __bf16 bf16x8 __attribute__((ext_vector_type(8)));
typedef float f32x4 __attribute__((ext_vector_type(4)));

#define D_DIM 4096
#define CTX_N 512
#define UPD_SCALE 9.5367431640625e-8f

__device__ __forceinline__ void gld16(const bf16_t* g, bf16_t* l) {
    __builtin_amdgcn_global_load_lds(
        (const __attribute__((address_space(1))) void*)g,
        (__attribute__((address_space(3))) void*)l, 16, 0, 0);
}

// ---- transpose+convert: src (M x N) fp32 tile -> dstT (N x M) bf16
//      [+ dstN (M x N) bf16].  64x64 tile at (bx,by); pad-65 (2-way = free).
__device__ __forceinline__ void t_body2(
    float* tile, const float* __restrict__ src, bf16_t* __restrict__ dstT,
    bf16_t* __restrict__ dstN, int M, int N, int bx, int by)
{
    const int tid = threadIdx.x;
    const int C0 = bx * 64, R0 = by * 64;
    const int r  = tid >> 2, cs = (tid & 3) * 16;

    const float* s = src + (size_t)(R0 + r) * N + C0 + cs;
    float f[16];
#pragma unroll
    for (int u = 0; u < 4; ++u) {
        const float4 v = ((const float4*)s)[u];
        f[4 * u + 0] = v.x; f[4 * u + 1] = v.y; f[4 * u + 2] = v.z; f[4 * u + 3] = v.w;
    }
#pragma unroll
    for (int u = 0; u < 16; ++u) tile[r * 65 + cs + u] = f[u];

    if (dstN) {
        bf16x8 v0, v1;
#pragma unroll
        for (int u = 0; u < 8; ++u) { v0[u] = (bf16_t)f[u]; v1[u] = (bf16_t)f[8 + u]; }
        bf16_t* d = dstN + (size_t)(R0 + r) * N + C0 + cs;
        *(bf16x8*)d = v0; *(bf16x8*)(d + 8) = v1;
    }
    __syncthreads();

    bf16x8 o0, o1;
#pragma unroll
    for (int u = 0; u < 8; ++u) {
        o0[u] = (bf16_t)tile[(cs + u) * 65 + r];
        o1[u] = (bf16_t)tile[(cs + 8 + u) * 65 + r];
    }
    bf16_t* d = dstT + (size_t)(C0 + r) * M + R0 + cs;
    *(bf16x8*)d = o0; *(bf16x8*)(d + 8) = o1;
}

// One launch for all three transposes: y<64 -> W, 64..71 -> K(+Kb), 72..79 -> V
__global__ __launch_bounds__(256) void t_all(
    const float* __restrict__ W, const float* __restrict__ K,
    const float* __restrict__ V, bf16_t* __restrict__ Wt,
    bf16_t* __restrict__ Kt, bf16_t* __restrict__ Kb, bf16_t* __restrict__ Vt)
{
    __shared__ float tile[64 * 65];
    const int y = blockIdx.y;
    if (y < 64)      t_body2(tile, W, Wt, nullptr, D_DIM, D_DIM, blockIdx.x, y);
    else if (y < 72) t_body2(tile, K, Kt, Kb,      CTX_N, D_DIM, blockIdx.x, y - 64);
    else             t_body2(tile, V, Vt, nullptr, CTX_N, D_DIM, blockIdx.x, y - 72);
}

// MFMA 16x16x32 bf16 (m89/m91): A/B frag: row=lane&15, k=quad*8+j (8 bf16);
// C/D: col=lane&15, row=quad*4+reg.  D[m][n] = sum_k A(m,k)*B(n,k).

// ---- K1: Rt[j][c] = sum_k Wt[j][k]*Kb[c][k] - Vt[j][c]  (4096 x 512) ----
// Barrier-free K-split: wave w owns k in [w*1024, w*1024+1024), 64x64 tile,
// per-wave DOUBLE-BUFFERED private staging (A0 B0 A1 B1, 4 KB each).
// Counted vmcnt: steady state waits vmcnt(12) (A of current tile) then
// vmcnt(8) (B of current tile) while the next tile's 8 loads stay in flight.
// grid (64 j, 8 c): id%8 = j%8 pins the 8 c-sharers of a Wt slice to one XCD.

#define K1_COMPUTE(BSEL, WA, WB)                                             \
    {                                                                        \
        const bf16_t* As = (const bf16_t*)(reg + (BSEL) * 8192);             \
        const bf16_t* Bs = (const bf16_t*)(reg + 4096 + (BSEL) * 8192);      \
        __builtin_amdgcn_s_waitcnt(WA);                                      \
        bf16x8 af[4];                                                        \
        _Pragma("unroll")                                                    \
        for (int mi = 0; mi < 4; ++mi)                                       \
            af[mi] = *(const bf16x8*)(As + (mi * 16 + l15) * 32 + quad * 8); \
        __builtin_amdgcn_s_waitcnt(WB);                                      \
        bf16x8 bq[4];                                                        \
        _Pragma("unroll")                                                    \
        for (int ni = 0; ni < 4; ++ni)                                       \
            bq[ni] = *(const bf16x8*)(Bs + (ni * 16 + l15) * 32 + quad * 8); \
        _Pragma("unroll")                                                    \
        for (int mi = 0; mi < 4; ++mi)                                       \
            _Pragma("unroll")                                                \
            for (int ni = 0; ni < 4; ++ni)                                   \
                acc[mi][ni] = __builtin_amdgcn_mfma_f32_16x16x32_bf16(       \
                    af[mi], bq[ni], acc[mi][ni], 0, 0, 0);                   \
    }

__global__ __launch_bounds__(256) void k1_residual(
    const bf16_t* __restrict__ Wt, const bf16_t* __restrict__ Kb,
    const bf16_t* __restrict__ Vt, bf16_t* __restrict__ Rt)
{
    __shared__ __align__(16) char smem[65536];  // 4 waves x (A0 B0 A1 B1)

    const int tid = threadIdx.x, wave = tid >> 6, lane = tid & 63;
    const int j0 = blockIdx.x * 64, c0 = blockIdx.y * 64;
    const int l15 = lane & 15, quad = lane >> 4;
    const int kw = wave * 1024;

    char* reg = smem + wave * 16384;  // private per-wave staging region

    f32x4 acc[4][4] = {};

    const int srow = lane >> 2, sseg = (lane & 3) * 8;   // 16 rows / gld16 call
    const bf16_t* ga = Wt + (size_t)(j0 + srow) * D_DIM + kw + sseg;
    const bf16_t* gb = Kb + (size_t)(c0 + srow) * D_DIM + kw + sseg;

    auto stageA = [&](int bsel, int ko) {
        bf16_t* la = (bf16_t*)(reg + bsel * 8192) + lane * 8;
#pragma unroll
        for (int c = 0; c < 4; ++c)
            gld16(ga + ko + (size_t)(c * 16) * D_DIM, la + c * 512);
    };
    auto stageB = [&](int bsel, int ko) {
        bf16_t* lb = (bf16_t*)(reg + 4096 + bsel * 8192) + lane * 8;
#pragma unroll
        for (int c = 0; c < 4; ++c)
            gld16(gb + ko + (size_t)(c * 16) * D_DIM, lb + c * 512);
    };

    // 32 K-tiles of 32. Prologue: tile 0 -> buf0 (8 loads outstanding).
    stageA(0, 0); stageB(0, 0);
#pragma unroll 1
    for (int t = 1; t <= 29; t += 2) {
        stageA(1, t * 32); stageB(1, t * 32);
        __builtin_amdgcn_sched_barrier(0);
        K1_COMPUTE(0, 0x0f7c, 0x0f78);            // tile t-1: vmcnt(12)/(8)
        stageA(0, (t + 1) * 32); stageB(0, (t + 1) * 32);
        __builtin_amdgcn_sched_barrier(0);
        K1_COMPUTE(1, 0x0f7c, 0x0f78);            // tile t
    }
    stageA(1, 31 * 32); stageB(1, 31 * 32);
    __builtin_amdgcn_sched_barrier(0);
    K1_COMPUTE(0, 0x0f7c, 0x0f78);                // tile 30
    K1_COMPUTE(1, 0x0f74, 0x0f70);                // tile 31: vmcnt(4)/(0)

    // Cross-wave reduction: ep[64][68] f32 (17.4 KB) aliases dead staging.
    float* ep = (float*)smem;
    __syncthreads();
#pragma unroll
    for (int w = 0; w < 4; ++w) {
        if (wave == w) {
#pragma unroll
            for (int mi = 0; mi < 4; ++mi)
#pragma unroll
                for (int ni = 0; ni < 4; ++ni)
#pragma unroll
                    for (int r = 0; r < 4; ++r) {
                        const int row = mi * 16 + quad * 4 + r;
                        const int col = ni * 16 + l15;
                        if (w == 0) ep[row * 68 + col]  = acc[mi][ni][r];
                        else        ep[row * 68 + col] += acc[mi][ni][r];
                    }
        }
        __syncthreads();
    }

    // Epilogue: Rt = ep - Vt, vectorized.
    {
        const int row = tid >> 2, cs = (tid & 3) * 16;
        const size_t rbase = (size_t)(j0 + row) * CTX_N + c0 + cs;
        float e[16];
#pragma unroll
        for (int u = 0; u < 4; ++u) {
            const float4 v = ((const float4*)(ep + row * 68 + cs))[u];
            e[4 * u + 0] = v.x; e[4 * u + 1] = v.y;
            e[4 * u + 2] = v.z; e[4 * u + 3] = v.w;
        }
        const bf16x8 v0 = *(const bf16x8*)(Vt + rbase);
        const bf16x8 v1 = *(const bf16x8*)(Vt + rbase + 8);
        bf16x8 o0, o1;
#pragma unroll
        for (int u = 0; u < 8; ++u) {
            o0[u] = (bf16_t)(e[u]     - (float)v0[u]);
            o1[u] = (bf16_t)(e[8 + u] - (float)v1[u]);
        }
        *(bf16x8*)(Rt + rbase)     = o0;
        *(bf16x8*)(Rt + rbase + 8) = o1;
    }
}

// ---- K2: out[i][j] = W[i][j] - c * sum_c Kt[i][c]*Rt[j][c]  (4096x4096) ----
// 128x128 tile, BK=32, 4 waves of 64x64. Double-buffered staging (2x16 KB):
// stage(t+1) issued before compute(t), one __syncthreads per K-step.
// Epilogue is BARRIER-FREE: direct per-fragment W load (prefetched one
// mi-block ahead, statically indexed), FMA, dword store. 16-lane 64B
// segments; ni-adjacent segments complete 256B row chunks -> L2 merges.
// Bijective XCD swizzle: 32 blocks sharing a Kt i-slice -> one XCD.

#define K2_COMPUTE(BSEL)                                                     \
    {                                                                        \
        const bf16_t* As = (const bf16_t*)(smem + (BSEL) * 16384);           \
        const bf16_t* Bs = (const bf16_t*)(smem + (BSEL) * 16384 + 8192);    \
        bf16x8 af[4], bq[4];                                                 \
        _Pragma("unroll")                                                    \
        for (int mi = 0; mi < 4; ++mi)                                       \
            af[mi] = *(const bf16x8*)(As + (wi + mi * 16 + l15) * 32 + quad * 8); \
        _Pragma("unroll")                                                    \
        for (int ni = 0; ni < 4; ++ni)                                       \
            bq[ni] = *(const bf16x8*)(Bs + (wj + ni * 16 + l15) * 32 + quad * 8); \
        _Pragma("unroll")                                                    \
        for (int mi = 0; mi < 4; ++mi)                                       \
            _Pragma("unroll")                                                \
            for (int ni = 0; ni < 4; ++ni)                                   \
                acc[mi][ni] = __builtin_amdgcn_mfma_f32_16x16x32_bf16(       \
                    af[mi], bq[ni], acc[mi][ni], 0, 0, 0);                   \
    }

__global__ __launch_bounds__(256) void k2_update(
    const bf16_t* __restrict__ Kt, const bf16_t* __restrict__ Rt,
    const float* __restrict__ W, float* __restrict__ out)
{
    __shared__ __align__(16) char smem[32768];  // buf0 16KB | buf1 16KB

    const int tid = threadIdx.x;

    // Bijective XCD swizzle: id = 8*xp + (yp&7) + 256*(yp>>3).
    // Same yp (same Kt i-slice) -> same id%8 -> same XCD L2.
    const int id = blockIdx.x + 32 * blockIdx.y;
    const int xp = (id >> 3) & 31;
    const int yp = (id & 7) + 8 * (id >> 8);
    const int j0 = xp * 128, i0 = yp * 128;

    const int lane = tid & 63, wave = tid >> 6;
    const int wi = (wave >> 1) * 64, wj = (wave & 1) * 64;
    const int l15 = lane & 15, quad = lane >> 4;

    f32x4 acc[4][4] = {};

    const bf16_t* ga = Kt + (size_t)(i0 + (tid >> 2)) * CTX_N + (tid & 3) * 8;
    const bf16_t* gb = Rt + (size_t)(j0 + (tid >> 2)) * CTX_N + (tid & 3) * 8;

    auto stage = [&](int bsel, int cc) {
        bf16_t* la = (bf16_t*)(smem + bsel * 16384) + tid * 8;
        bf16_t* lb = (bf16_t*)(smem + bsel * 16384 + 8192) + tid * 8;
        gld16(ga + cc, la);
        gld16(ga + cc + (size_t)64 * CTX_N, la + 64 * 32);
        gld16(gb + cc, lb);
        gld16(gb + cc + (size_t)64 * CTX_N, lb + 64 * 32);
    };

    // 16 K-tiles of 32. Prologue: tile 0 -> buf0.
    stage(0, 0);
    __syncthreads();
#pragma unroll 1
    for (int t = 1; t <= 13; t += 2) {
        stage(1, t * 32);
        __builtin_amdgcn_sched_barrier(0);
        K2_COMPUTE(0);                  // tile t-1
        __syncthreads();
        stage(0, (t + 1) * 32);
        __builtin_amdgcn_sched_barrier(0);
        K2_COMPUTE(1);                  // tile t
        __syncthreads();
    }
    stage(1, 15 * 32);
    __builtin_amdgcn_sched_barrier(0);
    K2_COMPUTE(0);                      // tile 14
    __syncthreads();
    K2_COMPUTE(1);                      // tile 15

    // ---- Barrier-free direct epilogue ----
    // acc[mi][ni][r] maps to row = i0+wi+mi*16+quad*4+r, col = j0+wj+ni*16+l15.
    const size_t base = (size_t)(i0 + wi + quad * 4) * D_DIM + j0 + wj + l15;
    const float* wp = W + base;
    float*       op = out + base;

    // Prefetch mi=0's 16 W fragments.
    float w0[16], w1[16];
#pragma unroll
    for (int r = 0; r < 4; ++r)
#pragma unroll
        for (int ni = 0; ni < 4; ++ni)
            w0[r * 4 + ni] = wp[(size_t)r * D_DIM + ni * 16];

#pragma unroll
    for (int mi = 0; mi < 4; ++mi) {
        float* wcur = (mi & 1) ? w1 : w0;
        float* wnxt = (mi & 1) ? w0 : w1;
        if (mi < 3) {
#pragma unroll
            for (int r = 0; r < 4; ++r)
#pragma unroll
                for (int ni = 0; ni < 4; ++ni)
                    wnxt[r * 4 + ni] =
                        wp[(size_t)((mi + 1) * 16 + r) * D_DIM + ni * 16];
        }
#pragma unroll
        for (int r = 0; r < 4; ++r)
#pragma unroll
            for (int ni = 0; ni < 4; ++ni)
                op[(size_t)(mi * 16 + r) * D_DIM + ni * 16] =
                    wcur[r * 4 + ni] - UPD_SCALE * acc[mi][ni][r];
    }
}

extern "C" void kernel_launch(void* const* d_in, const int* in_sizes, int n_in,
                              void* d_out, int out_size, void* d_ws, size_t ws_size,
                              hipStream_t stream) {
    const float* W = (const float*)d_in[0];   // (4096, 4096)
    const float* K = (const float*)d_in[1];   // (512, 4096)
    const float* V = (const float*)d_in[2];   // (512, 4096)
    float* out = (float*)d_out;

    char* ws = (char*)d_ws;                    // 48 MB used
    bf16_t* Wt = (bf16_t*)(ws);                            // (4096,4096) W^T
    bf16_t* Kt = (bf16_t*)(ws + (size_t)32 * 1024 * 1024); // (4096,512) K^T
    bf16_t* Kb = (bf16_t*)(ws + (size_t)36 * 1024 * 1024); // (512,4096) K
    bf16_t* Vt = (bf16_t*)(ws + (size_t)40 * 1024 * 1024); // (4096,512) V^T
    bf16_t* Rt = (bf16_t*)(ws + (size_t)44 * 1024 * 1024); // (4096,512) R^T

    t_all      <<<dim3(64, 80), 256, 0, stream>>>(W, K, V, Wt, Kt, Kb, Vt);
    k1_residual<<<dim3(64, 8),  256, 0, stream>>>(Wt, Kb, Vt, Rt);
    k2_update  <<<dim3(32, 32), 256, 0, stream>>>(Kt, Rt, W, out);
}